// Round 18
// baseline (486.936 us; speedup 1.0000x reference)
//
#include <hip/hip_runtime.h>
#include <math.h>

// ---------------- constants ----------------
static constexpr int NIMG = 16;
static constexpr int TOK  = NIMG * 56 * 56;          // 50176
static constexpr size_t TC = (size_t)TOK * 256;      // 12,845,056
static constexpr int PTOK = 784 * 16;                // 12544 pooled tokens

typedef __bf16 bf16x8 __attribute__((ext_vector_type(8)));
typedef float  f32x4  __attribute__((ext_vector_type(4)));

__device__ inline float bf2f(unsigned short u) {
  unsigned int i = ((unsigned int)u) << 16; float f; __builtin_memcpy(&f, &i, 4); return f;
}
__device__ inline unsigned short f2bf(float f) {
  unsigned int i; __builtin_memcpy(&i, &f, 4);
  unsigned int r = i + 0x7fffu + ((i >> 16) & 1u);
  return (unsigned short)(r >> 16);
}

// ---------------- fused NCHW-input 3x3 dwconv residual + LayerNorm1 ----------------
// Block = one image row (56 px) x 256 ch; 256 threads (w = tid>>2, q = tid&3).
// Reads x NCHW directly (w-contiguous, coalesced); halo rows L2-resident via
// XCD chunking. Writes r2 (NHWC f32) in pass 1; re-reads it (L2-hot) for lnb.
__global__ __launch_bounds__(256) void poslnT_kernel(const float* __restrict__ x,
                                                     const float* __restrict__ w,
                                                     const float* __restrict__ bb,
                                                     const float* __restrict__ g1,
                                                     const float* __restrict__ b1,
                                                     float* __restrict__ xh,
                                                     unsigned short* __restrict__ lnb,
                                                     float* __restrict__ murs) {
  int bid = blockIdx.x;
  int wgid = (bid & 7) * 112 + (bid >> 3);   // grid 896 = 8*112
  int n = wgid / 56, h = wgid % 56;
  int tid = threadIdx.x;
  int ww = tid >> 2;                          // 0..63 (active < 56)
  int q = tid & 3;
  bool act = ww < 56;
  int wcl = act ? ww : 55;

  const float* ximg = x + (size_t)n * 256 * 3136;
  int hm = h > 0 ? h - 1 : 0, hp = h < 55 ? h + 1 : 55;
  float mh0 = h > 0 ? 1.f : 0.f, mh2 = h < 55 ? 1.f : 0.f;
  int wm = wcl > 0 ? wcl - 1 : 0, wp = wcl < 55 ? wcl + 1 : 55;
  float mw0 = wcl > 0 ? 1.f : 0.f, mw2 = wcl < 55 ? 1.f : 0.f;

  size_t t = ((size_t)n * 56 + h) * 56 + wcl;
  float psum = 0.f, psq = 0.f;

#pragma unroll
  for (int cc = 0; cc < 8; cc++) {
    float vv[8];
#pragma unroll
    for (int j = 0; j < 8; j++) {
      int c = cc * 32 + q * 8 + j;
      const float* xc = ximg + (size_t)c * 3136;
      const float* r0 = xc + hm * 56;
      const float* r1 = xc + h * 56;
      const float* r2p = xc + hp * 56;
      float a = bb[c];
      a += r0[wm]  * (w[0 * 256 + c] * (mh0 * mw0));
      a += r0[wcl] * (w[1 * 256 + c] * mh0);
      a += r0[wp]  * (w[2 * 256 + c] * (mh0 * mw2));
      a += r1[wm]  * (w[3 * 256 + c] * mw0);
      float ctr = r1[wcl];
      a += ctr * w[4 * 256 + c];
      a += r1[wp]  * (w[5 * 256 + c] * mw2);
      a += r2p[wm]  * (w[6 * 256 + c] * (mh2 * mw0));
      a += r2p[wcl] * (w[7 * 256 + c] * mh2);
      a += r2p[wp]  * (w[8 * 256 + c] * (mh2 * mw2));
      float v = ctr + a;
      vv[j] = v;
      psum += v;
      psq += v * v;
    }
    if (act) {
      int c = cc * 32 + q * 8;
      f32x4 v0 = (f32x4){vv[0], vv[1], vv[2], vv[3]};
      f32x4 v1 = (f32x4){vv[4], vv[5], vv[6], vv[7]};
      *(f32x4*)&xh[t * 256 + c] = v0;
      *(f32x4*)&xh[t * 256 + c + 4] = v1;
    }
  }

  // reduce over the 4 q-lanes (aligned groups of 4 within a wave)
  psum += __shfl_xor(psum, 1); psum += __shfl_xor(psum, 2);
  psq  += __shfl_xor(psq, 1);  psq  += __shfl_xor(psq, 2);
  float mu = psum * (1.f / 256.f);
  float var = psq * (1.f / 256.f) - mu * mu;
  float rs = rsqrtf(var + 1e-6f);

  if (act) {
#pragma unroll
    for (int cc = 0; cc < 8; cc++) {
      int c = cc * 32 + q * 8;
      f32x4 v0 = *(const f32x4*)&xh[t * 256 + c];
      f32x4 v1 = *(const f32x4*)&xh[t * 256 + c + 4];
      f32x4 g0 = *(const f32x4*)&g1[c], g4 = *(const f32x4*)&g1[c + 4];
      f32x4 b0 = *(const f32x4*)&b1[c], b4 = *(const f32x4*)&b1[c + 4];
      f32x4 y0 = (v0 - mu) * rs * g0 + b0;
      f32x4 y1 = (v1 - mu) * rs * g4 + b4;
      unsigned short yb[8];
#pragma unroll
      for (int j = 0; j < 4; j++) { yb[j] = f2bf(y0[j]); yb[4 + j] = f2bf(y1[j]); }
      __builtin_memcpy(lnb + t * 256 + c, yb, 16);
    }
    if (q == 0) {
      murs[2 * t] = mu;
      murs[2 * t + 1] = rs;
    }
  }
}

// ---------------- MFMA bf16 GEMM v2 (BM=128,BN=256,BK=64, XCD-chunked, serial) ----
// flags: 1 = exact GELU, 2 = += R (f32, ld=N), 8 = skip bias
// LN2F: fused LayerNorm epilogue (N == 256, gx == 1, flags&2).
// NCHWOUT: final-output mode (N == 256, gx == 1): writes f32 NCHW directly to C_.
template <bool OUTBF, bool LN2F, bool NCHWOUT = false>
__global__ __launch_bounds__(512, 4) void mgemm2(const unsigned short* __restrict__ A, int lda,
                                                 const unsigned short* __restrict__ B, int ldb,
                                                 const float* __restrict__ bias,
                                                 const float* __restrict__ R,
                                                 void* __restrict__ C_,
                                                 int N, int K, int flags, int gx,
                                                 const float* __restrict__ g2,
                                                 const float* __restrict__ b2,
                                                 unsigned short* __restrict__ ob2) {
  __shared__ __attribute__((aligned(16))) char smraw[49152];
  unsigned short* As = (unsigned short*)smraw;
  unsigned short* Bs = (unsigned short*)(smraw + 16384);
  float* slab = (float*)smraw;
  constexpr int SSTR = 260;

  int tid = threadIdx.x;
  int nwg = gridDim.x, bid = blockIdx.x;
  int q8 = nwg >> 3, r8 = nwg & 7;
  int xcd = bid & 7, pos = bid >> 3;
  int wgid = (xcd < r8 ? xcd * (q8 + 1) : r8 * (q8 + 1) + (xcd - r8) * q8) + pos;
  int m0 = (wgid / gx) * 128;
  int n0 = (wgid % gx) * 256;

  int lane = tid & 63, wid = tid >> 6;
  int wr = (wid >> 2) * 64, wc = (wid & 3) * 64;
  int llo = lane & 15, lhi = lane >> 4;

  f32x4 acc[4][4];
#pragma unroll
  for (int i = 0; i < 4; i++)
#pragma unroll
    for (int j = 0; j < 4; j++) acc[i][j] = (f32x4){0.f, 0.f, 0.f, 0.f};

  for (int k0 = 0; k0 < K; k0 += 64) {
#pragma unroll
    for (int i = 0; i < 2; i++) {
      int qa = tid + 512 * i;
      int row = qa >> 3, col = (qa & 7) ^ (row & 7);
      __builtin_amdgcn_global_load_lds(
          (const __attribute__((address_space(1))) unsigned int*)
              (A + (size_t)(m0 + row) * lda + k0 + col * 8),
          (__attribute__((address_space(3))) unsigned int*)(As + qa * 8), 16, 0, 0);
    }
#pragma unroll
    for (int i = 0; i < 4; i++) {
      int qb = tid + 512 * i;
      int row = qb >> 3, col = (qb & 7) ^ (row & 7);
      __builtin_amdgcn_global_load_lds(
          (const __attribute__((address_space(1))) unsigned int*)
              (B + (size_t)(n0 + row) * ldb + k0 + col * 8),
          (__attribute__((address_space(3))) unsigned int*)(Bs + qb * 8), 16, 0, 0);
    }
    __syncthreads();
#pragma unroll
    for (int ks = 0; ks < 2; ks++) {
      int cchunk = ks * 4 + lhi;
      bf16x8 af[4], bfr[4];
#pragma unroll
      for (int mi = 0; mi < 4; mi++) {
        int r = wr + mi * 16 + llo;
        __builtin_memcpy(&af[mi], As + (size_t)r * 64 + (cchunk ^ (r & 7)) * 8, 16);
      }
#pragma unroll
      for (int nj = 0; nj < 4; nj++) {
        int r = wc + nj * 16 + llo;
        __builtin_memcpy(&bfr[nj], Bs + (size_t)r * 64 + (cchunk ^ (r & 7)) * 8, 16);
      }
#pragma unroll
      for (int mi = 0; mi < 4; mi++)
#pragma unroll
        for (int nj = 0; nj < 4; nj++)
          acc[mi][nj] = __builtin_amdgcn_mfma_f32_16x16x32_bf16(af[mi], bfr[nj],
                                                                acc[mi][nj], 0, 0, 0);
    }
    __syncthreads();
  }

  // ---- epilogue: 4 slabs of 32 rows ----
#pragma unroll
  for (int s = 0; s < 4; s++) {
    if (wr == (s >> 1) * 64) {
#pragma unroll
      for (int mi2 = 0; mi2 < 2; mi2++) {
        int mi = (s & 1) * 2 + mi2;
#pragma unroll
        for (int nj = 0; nj < 4; nj++) {
          int col = wc + nj * 16 + llo;
#pragma unroll
          for (int j = 0; j < 4; j++)
            slab[(mi2 * 16 + lhi * 4 + j) * SSTR + col] = acc[mi][nj][j];
        }
      }
    }
    __syncthreads();
    int gmBase = m0 + s * 32;
    if (OUTBF) {
#pragma unroll
      for (int i2 = 0; i2 < 2; i2++) {
        int rr = wid * 4 + i2 * 2 + (lane >> 5);
        int col = (lane & 31) * 8;
        f32x4 v0 = *(f32x4*)&slab[rr * SSTR + col];
        f32x4 v1 = *(f32x4*)&slab[rr * SSTR + col + 4];
        if (!(flags & 8)) {
          v0 += *(const f32x4*)&bias[n0 + col];
          v1 += *(const f32x4*)&bias[n0 + col + 4];
        }
        if (flags & 1) {
#pragma unroll
          for (int j = 0; j < 4; j++) {
            v0[j] = 0.5f * v0[j] * (1.0f + erff(v0[j] * 0.70710678118654752f));
            v1[j] = 0.5f * v1[j] * (1.0f + erff(v1[j] * 0.70710678118654752f));
          }
        }
        unsigned short ob[8];
#pragma unroll
        for (int j = 0; j < 4; j++) { ob[j] = f2bf(v0[j]); ob[4 + j] = f2bf(v1[j]); }
        __builtin_memcpy((unsigned short*)C_ + (size_t)(gmBase + rr) * N + n0 + col, ob, 16);
      }
    } else {
#pragma unroll
      for (int i = 0; i < 4; i++) {
        int rr = wid * 4 + i;
        int gm = gmBase + rr;
        int col = lane * 4;
        f32x4 v = *(f32x4*)&slab[rr * SSTR + col];
        if (!(flags & 8)) v += *(const f32x4*)&bias[n0 + col];
        if (flags & 1) {
#pragma unroll
          for (int j = 0; j < 4; j++)
            v[j] = 0.5f * v[j] * (1.0f + erff(v[j] * 0.70710678118654752f));
        }
        if (flags & 2) v += *(const f32x4*)&R[(size_t)gm * N + n0 + col];
        if (LN2F) {
          float sv = v[0] + v[1] + v[2] + v[3];
          float qv = v[0] * v[0] + v[1] * v[1] + v[2] * v[2] + v[3] * v[3];
#pragma unroll
          for (int d = 1; d < 64; d <<= 1) {
            sv += __shfl_xor(sv, d);
            qv += __shfl_xor(qv, d);
          }
          float mu = sv * (1.f / 256.f);
          float var = qv * (1.f / 256.f) - mu * mu;
          float rs = rsqrtf(var + 1e-6f);
          f32x4 g4 = *(const f32x4*)&g2[col];
          f32x4 b4 = *(const f32x4*)&b2[col];
          f32x4 y = (v - mu) * rs * g4 + b4;
          unsigned short yb[4];
#pragma unroll
          for (int j = 0; j < 4; j++) yb[j] = f2bf(y[j]);
          __builtin_memcpy(ob2 + (size_t)gm * 256 + col, yb, 8);
        }
        if (NCHWOUT) {
          *(f32x4*)&slab[rr * SSTR + col] = v;
        } else {
          *(f32x4*)&((float*)C_)[(size_t)gm * N + n0 + col] = v;
        }
      }
      if (NCHWOUT) {
        __syncthreads();
        int n_img = gmBase / 3136;
        int hwb = gmBase % 3136;
        int c = tid & 255, half = tid >> 8;
        float* dst = (float*)C_ + ((size_t)n_img * 256 + c) * 3136 + hwb + half * 16;
#pragma unroll
        for (int i2 = 0; i2 < 4; i2++) {
          f32x4 v2;
#pragma unroll
          for (int j = 0; j < 4; j++)
            v2[j] = slab[(half * 16 + i2 * 4 + j) * SSTR + c];
          *(f32x4*)&dst[i2 * 4] = v2;
        }
      }
    }
    __syncthreads();
  }
}

// ---------------- one-shot weight prep ----------------
__global__ __launch_bounds__(256) void prep_kernel(const float* __restrict__ qkv_w,
                                                   const float* __restrict__ qkv_b,
                                                   const float* __restrict__ wo_w,
                                                   const float* __restrict__ fc1_w,
                                                   const float* __restrict__ fc2_w,
                                                   const float* __restrict__ lepe_w,
                                                   unsigned short* __restrict__ wqv,
                                                   unsigned short* __restrict__ wkv,
                                                   unsigned short* __restrict__ wwo,
                                                   unsigned short* __restrict__ wfc1,
                                                   unsigned short* __restrict__ wfc2,
                                                   float* __restrict__ bqv,
                                                   unsigned short* __restrict__ wlep) {
  int i = blockIdx.x * 256 + threadIdx.x;
  if (i < 65536) { wqv[i] = f2bf(qkv_w[i]); }
  else if (i < 131072) { int j = i - 65536; wqv[65536 + j] = f2bf(qkv_w[512 * 256 + j]); }
  else if (i < 262144) { int j = i - 131072; wkv[j] = f2bf(qkv_w[256 * 256 + j]); }
  else if (i < 327680) { int j = i - 262144; wwo[j] = f2bf(wo_w[j]); }
  else if (i < 589824) { int j = i - 327680; wfc1[j] = f2bf(fc1_w[j]); }
  else if (i < 851968) { int j = i - 589824; wfc2[j] = f2bf(fc2_w[j]); }
  else if (i < 852480) { int j = i - 851968; bqv[j] = qkv_b[j < 256 ? j : j + 256]; }
  else if (i < 858880) { int j = i - 852480; wlep[j] = f2bf(lepe_w[j]); }
}

// ---------------- pool: LN applied on the fly from (xh, murs) ----------------
__global__ __launch_bounds__(256) void pool_kernel(const float* __restrict__ xh,
                                                   const float* __restrict__ murs,
                                                   const float* __restrict__ g1,
                                                   const float* __restrict__ b1,
                                                   unsigned short* __restrict__ plx,
                                                   float* __restrict__ wmx) {
  int np = blockIdx.x * 4 + (threadIdx.x >> 6);
  int lane = threadIdx.x & 63;
  int c = lane * 4;
  int n = np / 49, p = np % 49, wr = p / 7, wcq = p % 7;
  f32x4 g4 = *(const f32x4*)&g1[c];
  f32x4 b4 = *(const f32x4*)&b1[c];
  f32x4 tot = (f32x4){0.f, 0.f, 0.f, 0.f};
  for (int s = 0; s < 16; s++) {
    int i = s >> 2, j = s & 3;
    f32x4 z = (f32x4){0.f, 0.f, 0.f, 0.f};
    for (int di = 0; di < 2; di++)
      for (int dj = 0; dj < 2; dj++) {
        size_t t = ((size_t)n * 56 + wr * 8 + i * 2 + di) * 56 + wcq * 8 + j * 2 + dj;
        float mu = murs[2 * t], rs = murs[2 * t + 1];
        f32x4 v = *(const f32x4*)&xh[t * 256 + c];
        z += (v - mu) * rs;
      }
    z *= 0.25f;
    f32x4 cell = z * g4 + b4;
    unsigned short ab[4];
#pragma unroll
    for (int k = 0; k < 4; k++) ab[k] = f2bf(cell[k]);
    __builtin_memcpy(plx + ((size_t)np * 16 + s) * 256 + c, ab, 8);
    tot += z;
  }
  f32x4 wm = tot * (1.f / 16.f) * g4 + b4;
  *(f32x4*)&wmx[(size_t)np * 256 + c] = wm;
}

// ---------------- window-mean projection (f32) ----------------
__global__ __launch_bounds__(256) void winproj_kernel(const float* __restrict__ wmx,
                                                      const float* __restrict__ qkv_w,
                                                      const float* __restrict__ qkv_b,
                                                      float* __restrict__ qkwin) {
  int np = blockIdx.x, t = threadIdx.x;
  __shared__ float xs[256];
  xs[t] = wmx[(size_t)np * 256 + t];
  __syncthreads();
  for (int rep = 0; rep < 2; rep++) {
    int n = t + rep * 256;
    const float* wrow = qkv_w + (size_t)n * 256;
    float s = qkv_b[n];
    for (int c = 0; c < 256; c++) s += xs[c] * wrow[c];
    qkwin[(size_t)np * 512 + n] = s;
  }
}

// ---------------- routing logits + top-4 (set semantics) ----------------
__global__ __launch_bounds__(64) void topk_kernel(const float* __restrict__ qkwin,
                                                  int* __restrict__ idx) {
  int np = blockIdx.x;
  int n = np / 49;
  int j = threadIdx.x;
  __shared__ float lg[49];
  if (j < 49) {
    const float* qp = qkwin + (size_t)np * 512;
    const float* kp = qkwin + ((size_t)n * 49 + j) * 512 + 256;
    float s = 0.f;
    for (int c = 0; c < 256; c++) s += qp[c] * kp[c];
    lg[j] = s;
  }
  __syncthreads();
  if (j == 0) {
    unsigned long long used = 0ull;
    for (int t = 0; t < 4; t++) {
      float best = -INFINITY;
      int bi = 0;
      for (int q = 0; q < 49; q++)
        if (!((used >> q) & 1ull) && lg[q] > best) { best = lg[q]; bi = q; }
      idx[np * 4 + t] = bi;
      used |= (1ull << bi);
    }
  }
}

// ---------------- MFMA attention: one 64-lane wave per (window, head) ----------------
__global__ __launch_bounds__(64) void attn_mfma(const unsigned short* __restrict__ qvb,
                                                const unsigned short* __restrict__ kvp,
                                                const int* __restrict__ idx,
                                                unsigned short* __restrict__ out) {
  __shared__ unsigned short Vt[32 * 72];
  __shared__ unsigned short Pl[64 * 72];
  int bid = blockIdx.x;
  int head = bid & 7, np = bid >> 3;
  int n = np / 49, p = np % 49;
  int h0 = (p / 7) * 8, w0 = (p % 7) * 8;
  int lane = threadIdx.x;
  int lhi = lane >> 4, llo = lane & 15;

  int wi4[4];
#pragma unroll
  for (int t = 0; t < 4; t++) wi4[t] = idx[np * 4 + t];

#pragma unroll
  for (int it = 0; it < 4; it++) {
    int cell = lane >> 2;
    int chunk = lane & 3;
    int s = it * 16 + cell;
    const unsigned short* g = kvp + ((size_t)(n * 49 + wi4[it]) * 16 + cell) * 512
                              + 256 + head * 32 + chunk * 8;
    unsigned short vv[8];
    __builtin_memcpy(vv, g, 16);
#pragma unroll
    for (int j = 0; j < 8; j++) Vt[(chunk * 8 + j) * 72 + s] = vv[j];
  }

  bf16x8 qf[4], kf[4];
#pragma unroll
  for (int mi = 0; mi < 4; mi++) {
    int row = mi * 16 + llo;
    int h = h0 + (row >> 3), w = w0 + (row & 7);
    __builtin_memcpy(&qf[mi],
                     qvb + (((size_t)n * 56 + h) * 56 + w) * 512 + head * 32 + lhi * 8, 16);
  }
#pragma unroll
  for (int nj = 0; nj < 4; nj++) {
    __builtin_memcpy(&kf[nj],
                     kvp + ((size_t)(n * 49 + wi4[nj]) * 16 + llo) * 512 + head * 32 + lhi * 8,
                     16);
  }

  f32x4 acc[4][4];
#pragma unroll
  for (int mi = 0; mi < 4; mi++)
#pragma unroll
    for (int nj = 0; nj < 4; nj++) acc[mi][nj] = (f32x4){0.f, 0.f, 0.f, 0.f};
#pragma unroll
  for (int mi = 0; mi < 4; mi++)
#pragma unroll
    for (int nj = 0; nj < 4; nj++)
      acc[mi][nj] = __builtin_amdgcn_mfma_f32_16x16x32_bf16(qf[mi], kf[nj], acc[mi][nj], 0, 0, 0);

#pragma unroll
  for (int mi = 0; mi < 4; mi++)
#pragma unroll
    for (int nj = 0; nj < 4; nj++) acc[mi][nj] *= 0.0625f;
#pragma unroll
  for (int mi = 0; mi < 4; mi++) {
#pragma unroll
    for (int reg = 0; reg < 4; reg++) {
      float m = fmaxf(fmaxf(acc[mi][0][reg], acc[mi][1][reg]),
                      fmaxf(acc[mi][2][reg], acc[mi][3][reg]));
      m = fmaxf(m, __shfl_xor(m, 1));
      m = fmaxf(m, __shfl_xor(m, 2));
      m = fmaxf(m, __shfl_xor(m, 4));
      m = fmaxf(m, __shfl_xor(m, 8));
      float sum = 0.f;
#pragma unroll
      for (int nj = 0; nj < 4; nj++) {
        float e = __expf(acc[mi][nj][reg] - m);
        acc[mi][nj][reg] = e;
        sum += e;
      }
      sum += __shfl_xor(sum, 1);
      sum += __shfl_xor(sum, 2);
      sum += __shfl_xor(sum, 4);
      sum += __shfl_xor(sum, 8);
      float inv = 1.0f / sum;
#pragma unroll
      for (int nj = 0; nj < 4; nj++) acc[mi][nj][reg] *= inv;
    }
  }

#pragma unroll
  for (int mi = 0; mi < 4; mi++)
#pragma unroll
    for (int nj = 0; nj < 4; nj++)
#pragma unroll
      for (int reg = 0; reg < 4; reg++) {
        int row = mi * 16 + lhi * 4 + reg;
        Pl[row * 72 + nj * 16 + llo] = f2bf(acc[mi][nj][reg]);
      }

  f32x4 o[4][2];
#pragma unroll
  for (int mi = 0; mi < 4; mi++)
#pragma unroll
    for (int nc = 0; nc < 2; nc++) o[mi][nc] = (f32x4){0.f, 0.f, 0.f, 0.f};
#pragma unroll
  for (int ks = 0; ks < 2; ks++) {
    bf16x8 pa[4], vb[2];
#pragma unroll
    for (int mi = 0; mi < 4; mi++)
      __builtin_memcpy(&pa[mi], Pl + (mi * 16 + llo) * 72 + ks * 32 + lhi * 8, 16);
#pragma unroll
    for (int nc = 0; nc < 2; nc++)
      __builtin_memcpy(&vb[nc], Vt + (nc * 16 + llo) * 72 + ks * 32 + lhi * 8, 16);
#pragma unroll
    for (int mi = 0; mi < 4; mi++)
#pragma unroll
      for (int nc = 0; nc < 2; nc++)
        o[mi][nc] = __builtin_amdgcn_mfma_f32_16x16x32_bf16(pa[mi], vb[nc], o[mi][nc], 0, 0, 0);
  }

  __syncthreads();
#pragma unroll
  for (int mi = 0; mi < 4; mi++)
#pragma unroll
    for (int nc = 0; nc < 2; nc++)
#pragma unroll
      for (int reg = 0; reg < 4; reg++) {
        int row = mi * 16 + lhi * 4 + reg;
        Pl[row * 40 + nc * 16 + llo] = f2bf(o[mi][nc][reg]);
      }
  __syncthreads();
#pragma unroll
  for (int it = 0; it < 4; it++) {
    int slot = it * 64 + lane;
    int row = slot >> 2, cp = slot & 3;
    unsigned short ov[8];
    __builtin_memcpy(ov, Pl + row * 40 + cp * 8, 16);
    int h = h0 + (row >> 3), w = w0 + (row & 7);
    __builtin_memcpy(out + (((size_t)n * 56 + h) * 56 + w) * 256 + head * 32 + cp * 8, ov, 16);
  }
}

// ---------------- 5x5 dwconv (lepe) v4: LDS-staged row-segment tile ----------------
__global__ __launch_bounds__(256) void lepe_kernel(const unsigned short* __restrict__ qvb,
                                                   const unsigned short* __restrict__ wlep,
                                                   const float* __restrict__ b,
                                                   unsigned short* __restrict__ out) {
  __shared__ unsigned short Vs[60 * 272];
  int bid = blockIdx.x;
  int wgid = (bid & 7) * 784 + (bid >> 3);
  int tb = wgid * 8;
  int n = tb / 3136, rem = tb % 3136;
  int h0 = rem / 56, w0 = rem % 56;
  int tid = threadIdx.x;

  const unsigned short* vimg = qvb + (size_t)n * 3136 * 512 + 256;
  {
    int chunk = tid & 31;
    for (int s = tid >> 5; s < 60; s += 8) {
      int r = s / 12, cc = s % 12;
      int hh = h0 + r - 2; hh = hh < 0 ? 0 : (hh > 55 ? 55 : hh);
      int wcg = w0 + cc - 2; wcg = wcg < 0 ? 0 : (wcg > 55 ? 55 : wcg);
      unsigned short tmp[8];
      __builtin_memcpy(tmp, vimg + (size_t)(hh * 56 + wcg) * 512 + chunk * 8, 16);
      __builtin_memcpy(&Vs[s * 272 + chunk * 8], tmp, 16);
    }
  }
  __syncthreads();

  int px = tid >> 5;
  int cg = tid & 31;
  int c = cg * 8;
  int wq = w0 + px;

  float acc[8];
#pragma unroll
  for (int j = 0; j < 8; j++) acc[j] = b[c + j];

#pragma unroll
  for (int r = 0; r < 5; r++) {
    float hok = ((unsigned)(h0 + r - 2) < 56u) ? 1.f : 0.f;
#pragma unroll
    for (int dc = 0; dc < 5; dc++) {
      float m = hok * (((unsigned)(wq + dc - 2) < 56u) ? 1.f : 0.f);
      int slot = r * 12 + px + dc;
      unsigned short vv[8], wv[8];
      __builtin_memcpy(vv, &Vs[slot * 272 + cg * 8], 16);
      __builtin_memcpy(wv, wlep + (r * 5 + dc) * 256 + c, 16);
#pragma unroll
      for (int j = 0; j < 8; j++) acc[j] += bf2f(vv[j]) * (bf2f(wv[j]) * m);
    }
  }

  size_t o = (size_t)(tb + px) * 256 + c;
  unsigned short ov[8];
  __builtin_memcpy(ov, out + o, 16);
  unsigned short nv[8];
#pragma unroll
  for (int j = 0; j < 8; j++) nv[j] = f2bf(bf2f(ov[j]) + acc[j]);
  __builtin_memcpy(out + o, nv, 16);
}

// ---------------- launch ----------------
extern "C" void kernel_launch(void* const* d_in, const int* in_sizes, int n_in,
                              void* d_out, int out_size, void* d_ws, size_t ws_size,
                              hipStream_t stream) {
  const float* x      = (const float*)d_in[0];
  const float* pos_w  = (const float*)d_in[1];
  const float* pos_b  = (const float*)d_in[2];
  const float* ln1_g  = (const float*)d_in[3];
  const float* ln1_b  = (const float*)d_in[4];
  const float* ln2_g  = (const float*)d_in[5];
  const float* ln2_b  = (const float*)d_in[6];
  const float* qkv_w  = (const float*)d_in[7];
  const float* qkv_b  = (const float*)d_in[8];
  const float* wo_w   = (const float*)d_in[9];
  const float* wo_b   = (const float*)d_in[10];
  const float* lepe_w = (const float*)d_in[11];
  const float* lepe_b = (const float*)d_in[12];
  const float* fc1_w  = (const float*)d_in[13];
  const float* fc1_b  = (const float*)d_in[14];
  const float* fc2_w  = (const float*)d_in[15];
  const float* fc2_b  = (const float*)d_in[16];

  // d_out timeline: qvb (bf16 [TOK][512]) -> hbuf -> final NCHW f32 (fc2 epilogue)
  unsigned short* qvb  = (unsigned short*)d_out;
  unsigned short* hbuf = (unsigned short*)d_out;

  // ws arena (~101 MB base)
  float*          r2   = (float*)d_ws;
  float*          wmx  = r2 + TC;
  float*          qkw  = wmx + (size_t)784 * 256;
  float*          bqv  = qkw + (size_t)784 * 512;
  unsigned short* lnb  = (unsigned short*)(bqv + 512);
  unsigned short* aob  = lnb;
  unsigned short* ln2b = lnb;
  unsigned short* plx  = lnb + TC;
  unsigned short* kvp  = plx + (size_t)PTOK * 256;
  unsigned short* wqv  = kvp + (size_t)PTOK * 512;
  unsigned short* wkv  = wqv + (size_t)512 * 256;
  unsigned short* wwo  = wkv + (size_t)512 * 256;
  unsigned short* wfc1 = wwo + (size_t)256 * 256;
  unsigned short* wfc2 = wfc1 + (size_t)1024 * 256;
  int*            idx  = (int*)(wfc2 + (size_t)256 * 1024);
  float*          murs = (float*)(idx + 784 * 4);
  unsigned short* wlep = (unsigned short*)(murs + (size_t)TOK * 2);
  unsigned short* hfull = wlep + 6400;

  size_t base_bytes = (size_t)((char*)hfull - (char*)d_ws);
  bool fullmlp = ws_size >= base_bytes + (size_t)TOK * 1024 * 2;

  prep_kernel<<<3355, 256, 0, stream>>>(qkv_w, qkv_b, wo_w, fc1_w, fc2_w, lepe_w,
                                        wqv, wkv, wwo, wfc1, wfc2, bqv, wlep);
  // fused NCHW-in 3x3 dwconv + LN1: r2 (residual), lnb (bf16 LN), murs
  poslnT_kernel<<<896, 256, 0, stream>>>(x, pos_w, pos_b, ln1_g, ln1_b,
                                         r2, lnb, murs);
  pool_kernel<<<196, 256, 0, stream>>>(r2, murs, ln1_g, ln1_b, plx, wmx);
  mgemm2<true, false><<<784, 512, 0, stream>>>(lnb, 256, wqv, 256, bqv, nullptr,
                                               qvb, 512, 256, 0, 2,
                                               nullptr, nullptr, nullptr);
  mgemm2<true, false><<<196, 512, 0, stream>>>(plx, 256, wkv, 256, qkv_b + 256, nullptr,
                                               kvp, 512, 256, 0, 2,
                                               nullptr, nullptr, nullptr);
  winproj_kernel<<<784, 256, 0, stream>>>(wmx, qkv_w, qkv_b, qkw);
  topk_kernel<<<784, 64, 0, stream>>>(qkw, idx);
  attn_mfma<<<6272, 64, 0, stream>>>(qvb, kvp, idx, aob);
  lepe_kernel<<<TOK / 8, 256, 0, stream>>>(qvb, wlep, lepe_b, aob);
  mgemm2<false, true><<<392, 512, 0, stream>>>(aob, 256, wwo, 256, wo_b, r2,
                                               r2, 256, 256, 2, 1,
                                               ln2_g, ln2_b, ln2b);
  if (fullmlp) {
    mgemm2<true, false><<<1568, 512, 0, stream>>>(ln2b, 256, wfc1, 256, fc1_b, nullptr,
                                                  hfull, 1024, 256, 1, 4,
                                                  nullptr, nullptr, nullptr);
    mgemm2<false, false, true><<<392, 512, 0, stream>>>(hfull, 1024, wfc2, 1024, fc2_b, r2,
                                                        d_out, 256, 1024, 2, 1,
                                                        nullptr, nullptr, nullptr);
  } else {
    mgemm2<true, false><<<784, 512, 0, stream>>>(ln2b, 256, wfc1, 256, fc1_b, nullptr,
                                                 hbuf, 512, 256, 1, 2,
                                                 nullptr, nullptr, nullptr);
    mgemm2<false, false><<<392, 512, 0, stream>>>(hbuf, 512, wfc2, 1024, fc2_b, r2,
                                                  r2, 256, 512, 2, 1,
                                                  nullptr, nullptr, nullptr);
    mgemm2<true, false><<<784, 512, 0, stream>>>(ln2b, 256, wfc1 + (size_t)512 * 256, 256,
                                                 fc1_b + 512, nullptr,
                                                 hbuf, 512, 256, 1, 2,
                                                 nullptr, nullptr, nullptr);
    mgemm2<false, false, true><<<392, 512, 0, stream>>>(hbuf, 512, wfc2 + 512, 1024, fc2_b, r2,
                                                        d_out, 256, 512, 2 | 8, 1,
                                                        nullptr, nullptr, nullptr);
  }
}

// Round 19
// 429.775 us; speedup vs baseline: 1.1330x; 1.1330x over previous
//
#include <hip/hip_runtime.h>
#include <math.h>

// ---------------- constants ----------------
static constexpr int NIMG = 16;
static constexpr int TOK  = NIMG * 56 * 56;          // 50176
static constexpr size_t TC = (size_t)TOK * 256;      // 12,845,056
static constexpr int PTOK = 784 * 16;                // 12544 pooled tokens

typedef __bf16 bf16x8 __attribute__((ext_vector_type(8)));
typedef float  f32x4  __attribute__((ext_vector_type(4)));

__device__ inline float bf2f(unsigned short u) {
  unsigned int i = ((unsigned int)u) << 16; float f; __builtin_memcpy(&f, &i, 4); return f;
}
__device__ inline unsigned short f2bf(float f) {
  unsigned int i; __builtin_memcpy(&i, &f, 4);
  unsigned int r = i + 0x7fffu + ((i >> 16) & 1u);
  return (unsigned short)(r >> 16);
}

// ---------------- transpose NCHW -> NHWC (float4 both sides) ----------------
__global__ __launch_bounds__(256) void nchw2nhwc(const float* __restrict__ x,
                                                 float* __restrict__ y) {
  __shared__ float T[32][37];
  int nh = blockIdx.z;
  int n = nh / 56, h = nh % 56;
  int c0 = blockIdx.y * 32, w0 = blockIdx.x * 32;
  int tid = threadIdx.x;
  int wlim = 56 - w0; if (wlim > 32) wlim = 32;
  {
    int ci = tid >> 3, w = (tid & 7) * 4;
    if (w < wlim) {
      f32x4 v = *(const f32x4*)&x[(((size_t)n * 256 + c0 + ci) * 56 + h) * 56 + w0 + w];
#pragma unroll
      for (int j = 0; j < 4; j++) T[ci][w + j] = v[j];
    }
  }
  __syncthreads();
  {
    int wi = tid >> 3, cq = tid & 7;
    if (wi < wlim) {
      f32x4 o;
#pragma unroll
      for (int k = 0; k < 4; k++) o[k] = T[cq * 4 + k][wi];
      *(f32x4*)&y[(((size_t)n * 56 + h) * 56 + w0 + wi) * 256 + c0 + cq * 4] = o;
    }
  }
}

// ---------------- fused 3x3 dwconv residual + LayerNorm1 ----------------
__global__ __launch_bounds__(256) void posln_kernel(const float* __restrict__ xt,
                                                    const float* __restrict__ w,
                                                    const float* __restrict__ bb,
                                                    const float* __restrict__ g1,
                                                    const float* __restrict__ b1,
                                                    float* __restrict__ xh,
                                                    unsigned short* __restrict__ lnb,
                                                    float* __restrict__ murs) {
  int bid = blockIdx.x;
  int wgid = (bid & 7) * 1568 + (bid >> 3);     // grid 12544 = 8*1568
  int t = wgid * 4 + (threadIdx.x >> 6);
  int lane = threadIdx.x & 63;
  int c = lane * 4;
  int n = t / 3136, rem = t % 3136, h = rem / 56, ww = rem % 56;
  const float* base = xt + (size_t)n * 3136 * 256 + c;

  f32x4 xx[9]; float msk[9];
#pragma unroll
  for (int k = 0; k < 9; k++) {
    int dh = k / 3 - 1, dw = k % 3 - 1;
    int hh = h + dh, wc = ww + dw;
    msk[k] = ((unsigned)hh < 56u && (unsigned)wc < 56u) ? 1.f : 0.f;
    int hcl = hh < 0 ? 0 : (hh > 55 ? 55 : hh);
    int wcl = wc < 0 ? 0 : (wc > 55 ? 55 : wc);
    xx[k] = *(const f32x4*)&base[(size_t)(hcl * 56 + wcl) * 256];
  }
  f32x4 acc = *(const f32x4*)&bb[c];
#pragma unroll
  for (int k = 0; k < 9; k++) {
    f32x4 wv = *(const f32x4*)&w[k * 256 + c];
    acc += xx[k] * (wv * msk[k]);
  }
  f32x4 v = xx[4] + acc;
  *(f32x4*)&xh[(size_t)t * 256 + c] = v;

  float s = v[0] + v[1] + v[2] + v[3];
#pragma unroll
  for (int m = 1; m < 64; m <<= 1) s += __shfl_xor(s, m);
  float mu = s * (1.f / 256.f);
  f32x4 d = v - mu;
  float ss = d[0] * d[0] + d[1] * d[1] + d[2] * d[2] + d[3] * d[3];
#pragma unroll
  for (int m = 1; m < 64; m <<= 1) ss += __shfl_xor(ss, m);
  float rs = rsqrtf(ss * (1.f / 256.f) + 1e-6f);
  f32x4 gg = *(const f32x4*)&g1[c];
  f32x4 b4 = *(const f32x4*)&b1[c];
  f32x4 y = d * rs * gg + b4;
  unsigned short yb[4];
#pragma unroll
  for (int j = 0; j < 4; j++) yb[j] = f2bf(y[j]);
  __builtin_memcpy(lnb + (size_t)t * 256 + c, yb, 8);
  if (lane == 0) {
    murs[2 * (size_t)t] = mu;
    murs[2 * (size_t)t + 1] = rs;
  }
}

// ---------------- MFMA bf16 GEMM v2 (BM=128,BN=256,BK=64, XCD-chunked) ------------
// flags: 1 = exact GELU, 2 = += R (f32, ld=N), 8 = skip bias
// LN2F: fused LayerNorm epilogue (N == 256, gx == 1, flags&2).
// NCHWOUT: final-output mode (N == 256, gx == 1): writes f32 NCHW directly to C_.
template <bool OUTBF, bool LN2F, bool NCHWOUT = false>
__global__ __launch_bounds__(512, 4) void mgemm2(const unsigned short* __restrict__ A, int lda,
                                                 const unsigned short* __restrict__ B, int ldb,
                                                 const float* __restrict__ bias,
                                                 const float* __restrict__ R,
                                                 void* __restrict__ C_,
                                                 int N, int K, int flags, int gx,
                                                 const float* __restrict__ g2,
                                                 const float* __restrict__ b2,
                                                 unsigned short* __restrict__ ob2) {
  __shared__ __attribute__((aligned(16))) char smraw[49152];
  unsigned short* As = (unsigned short*)smraw;
  unsigned short* Bs = (unsigned short*)(smraw + 16384);
  float* slab = (float*)smraw;
  constexpr int SSTR = 260;

  int tid = threadIdx.x;
  int nwg = gridDim.x, bid = blockIdx.x;
  int q8 = nwg >> 3, r8 = nwg & 7;
  int xcd = bid & 7, pos = bid >> 3;
  int wgid = (xcd < r8 ? xcd * (q8 + 1) : r8 * (q8 + 1) + (xcd - r8) * q8) + pos;
  int m0 = (wgid / gx) * 128;
  int n0 = (wgid % gx) * 256;

  int lane = tid & 63, wid = tid >> 6;
  int wr = (wid >> 2) * 64, wc = (wid & 3) * 64;
  int llo = lane & 15, lhi = lane >> 4;

  f32x4 acc[4][4];
#pragma unroll
  for (int i = 0; i < 4; i++)
#pragma unroll
    for (int j = 0; j < 4; j++) acc[i][j] = (f32x4){0.f, 0.f, 0.f, 0.f};

  for (int k0 = 0; k0 < K; k0 += 64) {
#pragma unroll
    for (int i = 0; i < 2; i++) {
      int qa = tid + 512 * i;
      int row = qa >> 3, col = (qa & 7) ^ (row & 7);
      __builtin_amdgcn_global_load_lds(
          (const __attribute__((address_space(1))) unsigned int*)
              (A + (size_t)(m0 + row) * lda + k0 + col * 8),
          (__attribute__((address_space(3))) unsigned int*)(As + qa * 8), 16, 0, 0);
    }
#pragma unroll
    for (int i = 0; i < 4; i++) {
      int qb = tid + 512 * i;
      int row = qb >> 3, col = (qb & 7) ^ (row & 7);
      __builtin_amdgcn_global_load_lds(
          (const __attribute__((address_space(1))) unsigned int*)
              (B + (size_t)(n0 + row) * ldb + k0 + col * 8),
          (__attribute__((address_space(3))) unsigned int*)(Bs + qb * 8), 16, 0, 0);
    }
    __syncthreads();
#pragma unroll
    for (int ks = 0; ks < 2; ks++) {
      int cchunk = ks * 4 + lhi;
      bf16x8 af[4], bfr[4];
#pragma unroll
      for (int mi = 0; mi < 4; mi++) {
        int r = wr + mi * 16 + llo;
        __builtin_memcpy(&af[mi], As + (size_t)r * 64 + (cchunk ^ (r & 7)) * 8, 16);
      }
#pragma unroll
      for (int nj = 0; nj < 4; nj++) {
        int r = wc + nj * 16 + llo;
        __builtin_memcpy(&bfr[nj], Bs + (size_t)r * 64 + (cchunk ^ (r & 7)) * 8, 16);
      }
#pragma unroll
      for (int mi = 0; mi < 4; mi++)
#pragma unroll
        for (int nj = 0; nj < 4; nj++)
          acc[mi][nj] = __builtin_amdgcn_mfma_f32_16x16x32_bf16(af[mi], bfr[nj],
                                                                acc[mi][nj], 0, 0, 0);
    }
    __syncthreads();
  }

  // ---- epilogue: 4 slabs of 32 rows ----
#pragma unroll
  for (int s = 0; s < 4; s++) {
    if (wr == (s >> 1) * 64) {
#pragma unroll
      for (int mi2 = 0; mi2 < 2; mi2++) {
        int mi = (s & 1) * 2 + mi2;
#pragma unroll
        for (int nj = 0; nj < 4; nj++) {
          int col = wc + nj * 16 + llo;
#pragma unroll
          for (int j = 0; j < 4; j++)
            slab[(mi2 * 16 + lhi * 4 + j) * SSTR + col] = acc[mi][nj][j];
        }
      }
    }
    __syncthreads();
    int gmBase = m0 + s * 32;
    if (OUTBF) {
#pragma unroll
      for (int i2 = 0; i2 < 2; i2++) {
        int rr = wid * 4 + i2 * 2 + (lane >> 5);
        int col = (lane & 31) * 8;
        f32x4 v0 = *(f32x4*)&slab[rr * SSTR + col];
        f32x4 v1 = *(f32x4*)&slab[rr * SSTR + col + 4];
        if (!(flags & 8)) {
          v0 += *(const f32x4*)&bias[n0 + col];
          v1 += *(const f32x4*)&bias[n0 + col + 4];
        }
        if (flags & 1) {
#pragma unroll
          for (int j = 0; j < 4; j++) {
            v0[j] = 0.5f * v0[j] * (1.0f + erff(v0[j] * 0.70710678118654752f));
            v1[j] = 0.5f * v1[j] * (1.0f + erff(v1[j] * 0.70710678118654752f));
          }
        }
        unsigned short ob[8];
#pragma unroll
        for (int j = 0; j < 4; j++) { ob[j] = f2bf(v0[j]); ob[4 + j] = f2bf(v1[j]); }
        __builtin_memcpy((unsigned short*)C_ + (size_t)(gmBase + rr) * N + n0 + col, ob, 16);
      }
    } else {
#pragma unroll
      for (int i = 0; i < 4; i++) {
        int rr = wid * 4 + i;
        int gm = gmBase + rr;
        int col = lane * 4;
        f32x4 v = *(f32x4*)&slab[rr * SSTR + col];
        if (!(flags & 8)) v += *(const f32x4*)&bias[n0 + col];
        if (flags & 1) {
#pragma unroll
          for (int j = 0; j < 4; j++)
            v[j] = 0.5f * v[j] * (1.0f + erff(v[j] * 0.70710678118654752f));
        }
        if (flags & 2) v += *(const f32x4*)&R[(size_t)gm * N + n0 + col];
        if (LN2F) {
          float sv = v[0] + v[1] + v[2] + v[3];
          float qv = v[0] * v[0] + v[1] * v[1] + v[2] * v[2] + v[3] * v[3];
#pragma unroll
          for (int d = 1; d < 64; d <<= 1) {
            sv += __shfl_xor(sv, d);
            qv += __shfl_xor(qv, d);
          }
          float mu = sv * (1.f / 256.f);
          float var = qv * (1.f / 256.f) - mu * mu;
          float rs = rsqrtf(var + 1e-6f);
          f32x4 g4 = *(const f32x4*)&g2[col];
          f32x4 b4 = *(const f32x4*)&b2[col];
          f32x4 y = (v - mu) * rs * g4 + b4;
          unsigned short yb[4];
#pragma unroll
          for (int j = 0; j < 4; j++) yb[j] = f2bf(y[j]);
          __builtin_memcpy(ob2 + (size_t)gm * 256 + col, yb, 8);
        }
        if (NCHWOUT) {
          *(f32x4*)&slab[rr * SSTR + col] = v;   // keep in slab for NCHW pass
        } else {
          *(f32x4*)&((float*)C_)[(size_t)gm * N + n0 + col] = v;
        }
      }
      if (NCHWOUT) {
        __syncthreads();
        // 32 rows x 256 ch -> NCHW; 3136 % 32 == 0 so slab is within one image
        int n_img = gmBase / 3136;
        int hwb = gmBase % 3136;
        int c = tid & 255, half = tid >> 8;
        float* dst = (float*)C_ + ((size_t)n_img * 256 + c) * 3136 + hwb + half * 16;
#pragma unroll
        for (int i2 = 0; i2 < 4; i2++) {
          f32x4 v2;
#pragma unroll
          for (int j = 0; j < 4; j++)
            v2[j] = slab[(half * 16 + i2 * 4 + j) * SSTR + c];
          *(f32x4*)&dst[i2 * 4] = v2;
        }
      }
    }
    __syncthreads();
  }
}

// ---------------- one-shot weight prep ----------------
__global__ __launch_bounds__(256) void prep_kernel(const float* __restrict__ qkv_w,
                                                   const float* __restrict__ qkv_b,
                                                   const float* __restrict__ wo_w,
                                                   const float* __restrict__ fc1_w,
                                                   const float* __restrict__ fc2_w,
                                                   const float* __restrict__ lepe_w,
                                                   unsigned short* __restrict__ wqv,
                                                   unsigned short* __restrict__ wkv,
                                                   unsigned short* __restrict__ wwo,
                                                   unsigned short* __restrict__ wfc1,
                                                   unsigned short* __restrict__ wfc2,
                                                   float* __restrict__ bqv,
                                                   unsigned short* __restrict__ wlep) {
  int i = blockIdx.x * 256 + threadIdx.x;
  if (i < 65536) { wqv[i] = f2bf(qkv_w[i]); }
  else if (i < 131072) { int j = i - 65536; wqv[65536 + j] = f2bf(qkv_w[512 * 256 + j]); }
  else if (i < 262144) { int j = i - 131072; wkv[j] = f2bf(qkv_w[256 * 256 + j]); }
  else if (i < 327680) { int j = i - 262144; wwo[j] = f2bf(wo_w[j]); }
  else if (i < 589824) { int j = i - 327680; wfc1[j] = f2bf(fc1_w[j]); }
  else if (i < 851968) { int j = i - 589824; wfc2[j] = f2bf(fc2_w[j]); }
  else if (i < 852480) { int j = i - 851968; bqv[j] = qkv_b[j < 256 ? j : j + 256]; }
  else if (i < 858880) { int j = i - 852480; wlep[j] = f2bf(lepe_w[j]); }
}

// ---------------- pool: LN applied on the fly from (xh, murs) ----------------
__global__ __launch_bounds__(256) void pool_kernel(const float* __restrict__ xh,
                                                   const float* __restrict__ murs,
                                                   const float* __restrict__ g1,
                                                   const float* __restrict__ b1,
                                                   unsigned short* __restrict__ plx,
                                                   float* __restrict__ wmx) {
  int np = blockIdx.x * 4 + (threadIdx.x >> 6);
  int lane = threadIdx.x & 63;
  int c = lane * 4;
  int n = np / 49, p = np % 49, wr = p / 7, wcq = p % 7;
  f32x4 g4 = *(const f32x4*)&g1[c];
  f32x4 b4 = *(const f32x4*)&b1[c];
  f32x4 tot = (f32x4){0.f, 0.f, 0.f, 0.f};
  for (int s = 0; s < 16; s++) {
    int i = s >> 2, j = s & 3;
    f32x4 z = (f32x4){0.f, 0.f, 0.f, 0.f};
    for (int di = 0; di < 2; di++)
      for (int dj = 0; dj < 2; dj++) {
        size_t t = ((size_t)n * 56 + wr * 8 + i * 2 + di) * 56 + wcq * 8 + j * 2 + dj;
        float mu = murs[2 * t], rs = murs[2 * t + 1];
        f32x4 v = *(const f32x4*)&xh[t * 256 + c];
        z += (v - mu) * rs;
      }
    z *= 0.25f;
    f32x4 cell = z * g4 + b4;
    unsigned short ab[4];
#pragma unroll
    for (int k = 0; k < 4; k++) ab[k] = f2bf(cell[k]);
    __builtin_memcpy(plx + ((size_t)np * 16 + s) * 256 + c, ab, 8);
    tot += z;
  }
  f32x4 wm = tot * (1.f / 16.f) * g4 + b4;
  *(f32x4*)&wmx[(size_t)np * 256 + c] = wm;
}

// ---------------- window-mean projection (f32) ----------------
__global__ __launch_bounds__(256) void winproj_kernel(const float* __restrict__ wmx,
                                                      const float* __restrict__ qkv_w,
                                                      const float* __restrict__ qkv_b,
                                                      float* __restrict__ qkwin) {
  int np = blockIdx.x, t = threadIdx.x;
  __shared__ float xs[256];
  xs[t] = wmx[(size_t)np * 256 + t];
  __syncthreads();
  for (int rep = 0; rep < 2; rep++) {
    int n = t + rep * 256;
    const float* wrow = qkv_w + (size_t)n * 256;
    float s = qkv_b[n];
    for (int c = 0; c < 256; c++) s += xs[c] * wrow[c];
    qkwin[(size_t)np * 512 + n] = s;
  }
}

// ---------------- routing logits + top-4 (set semantics) ----------------
__global__ __launch_bounds__(64) void topk_kernel(const float* __restrict__ qkwin,
                                                  int* __restrict__ idx) {
  int np = blockIdx.x;
  int n = np / 49;
  int j = threadIdx.x;
  __shared__ float lg[49];
  if (j < 49) {
    const float* qp = qkwin + (size_t)np * 512;
    const float* kp = qkwin + ((size_t)n * 49 + j) * 512 + 256;
    float s = 0.f;
    for (int c = 0; c < 256; c++) s += qp[c] * kp[c];
    lg[j] = s;
  }
  __syncthreads();
  if (j == 0) {
    unsigned long long used = 0ull;
    for (int t = 0; t < 4; t++) {
      float best = -INFINITY;
      int bi = 0;
      for (int q = 0; q < 49; q++)
        if (!((used >> q) & 1ull) && lg[q] > best) { best = lg[q]; bi = q; }
      idx[np * 4 + t] = bi;
      used |= (1ull << bi);
    }
  }
}

// ---------------- MFMA attention: one 64-lane wave per (window, head) ----------------
__global__ __launch_bounds__(64) void attn_mfma(const unsigned short* __restrict__ qvb,
                                                const unsigned short* __restrict__ kvp,
                                                const int* __restrict__ idx,
                                                unsigned short* __restrict__ out) {
  __shared__ unsigned short Vt[32 * 72];
  __shared__ unsigned short Pl[64 * 72];
  int bid = blockIdx.x;
  int head = bid & 7, np = bid >> 3;
  int n = np / 49, p = np % 49;
  int h0 = (p / 7) * 8, w0 = (p % 7) * 8;
  int lane = threadIdx.x;
  int lhi = lane >> 4, llo = lane & 15;

  int wi4[4];
#pragma unroll
  for (int t = 0; t < 4; t++) wi4[t] = idx[np * 4 + t];

#pragma unroll
  for (int it = 0; it < 4; it++) {
    int cell = lane >> 2;
    int chunk = lane & 3;
    int s = it * 16 + cell;
    const unsigned short* g = kvp + ((size_t)(n * 49 + wi4[it]) * 16 + cell) * 512
                              + 256 + head * 32 + chunk * 8;
    unsigned short vv[8];
    __builtin_memcpy(vv, g, 16);
#pragma unroll
    for (int j = 0; j < 8; j++) Vt[(chunk * 8 + j) * 72 + s] = vv[j];
  }

  bf16x8 qf[4], kf[4];
#pragma unroll
  for (int mi = 0; mi < 4; mi++) {
    int row = mi * 16 + llo;
    int h = h0 + (row >> 3), w = w0 + (row & 7);
    __builtin_memcpy(&qf[mi],
                     qvb + (((size_t)n * 56 + h) * 56 + w) * 512 + head * 32 + lhi * 8, 16);
  }
#pragma unroll
  for (int nj = 0; nj < 4; nj++) {
    __builtin_memcpy(&kf[nj],
                     kvp + ((size_t)(n * 49 + wi4[nj]) * 16 + llo) * 512 + head * 32 + lhi * 8,
                     16);
  }

  f32x4 acc[4][4];
#pragma unroll
  for (int mi = 0; mi < 4; mi++)
#pragma unroll
    for (int nj = 0; nj < 4; nj++) acc[mi][nj] = (f32x4){0.f, 0.f, 0.f, 0.f};
#pragma unroll
  for (int mi = 0; mi < 4; mi++)
#pragma unroll
    for (int nj = 0; nj < 4; nj++)
      acc[mi][nj] = __builtin_amdgcn_mfma_f32_16x16x32_bf16(qf[mi], kf[nj], acc[mi][nj], 0, 0, 0);

#pragma unroll
  for (int mi = 0; mi < 4; mi++)
#pragma unroll
    for (int nj = 0; nj < 4; nj++) acc[mi][nj] *= 0.0625f;
#pragma unroll
  for (int mi = 0; mi < 4; mi++) {
#pragma unroll
    for (int reg = 0; reg < 4; reg++) {
      float m = fmaxf(fmaxf(acc[mi][0][reg], acc[mi][1][reg]),
                      fmaxf(acc[mi][2][reg], acc[mi][3][reg]));
      m = fmaxf(m, __shfl_xor(m, 1));
      m = fmaxf(m, __shfl_xor(m, 2));
      m = fmaxf(m, __shfl_xor(m, 4));
      m = fmaxf(m, __shfl_xor(m, 8));
      float sum = 0.f;
#pragma unroll
      for (int nj = 0; nj < 4; nj++) {
        float e = __expf(acc[mi][nj][reg] - m);
        acc[mi][nj][reg] = e;
        sum += e;
      }
      sum += __shfl_xor(sum, 1);
      sum += __shfl_xor(sum, 2);
      sum += __shfl_xor(sum, 4);
      sum += __shfl_xor(sum, 8);
      float inv = 1.0f / sum;
#pragma unroll
      for (int nj = 0; nj < 4; nj++) acc[mi][nj][reg] *= inv;
    }
  }

#pragma unroll
  for (int mi = 0; mi < 4; mi++)
#pragma unroll
    for (int nj = 0; nj < 4; nj++)
#pragma unroll
      for (int reg = 0; reg < 4; reg++) {
        int row = mi * 16 + lhi * 4 + reg;
        Pl[row * 72 + nj * 16 + llo] = f2bf(acc[mi][nj][reg]);
      }

  f32x4 o[4][2];
#pragma unroll
  for (int mi = 0; mi < 4; mi++)
#pragma unroll
    for (int nc = 0; nc < 2; nc++) o[mi][nc] = (f32x4){0.f, 0.f, 0.f, 0.f};
#pragma unroll
  for (int ks = 0; ks < 2; ks++) {
    bf16x8 pa[4], vb[2];
#pragma unroll
    for (int mi = 0; mi < 4; mi++)
      __builtin_memcpy(&pa[mi], Pl + (mi * 16 + llo) * 72 + ks * 32 + lhi * 8, 16);
#pragma unroll
    for (int nc = 0; nc < 2; nc++)
      __builtin_memcpy(&vb[nc], Vt + (nc * 16 + llo) * 72 + ks * 32 + lhi * 8, 16);
#pragma unroll
    for (int mi = 0; mi < 4; mi++)
#pragma unroll
      for (int nc = 0; nc < 2; nc++)
        o[mi][nc] = __builtin_amdgcn_mfma_f32_16x16x32_bf16(pa[mi], vb[nc], o[mi][nc], 0, 0, 0);
  }

  // ---- stage o -> LDS (bf16 [64][40]) then 16B coalesced stores ----
  __syncthreads();
#pragma unroll
  for (int mi = 0; mi < 4; mi++)
#pragma unroll
    for (int nc = 0; nc < 2; nc++)
#pragma unroll
      for (int reg = 0; reg < 4; reg++) {
        int row = mi * 16 + lhi * 4 + reg;
        Pl[row * 40 + nc * 16 + llo] = f2bf(o[mi][nc][reg]);
      }
  __syncthreads();
#pragma unroll
  for (int it = 0; it < 4; it++) {
    int slot = it * 64 + lane;
    int row = slot >> 2, cp = slot & 3;
    unsigned short ov[8];
    __builtin_memcpy(ov, Pl + row * 40 + cp * 8, 16);
    int h = h0 + (row >> 3), w = w0 + (row & 7);
    __builtin_memcpy(out + (((size_t)n * 56 + h) * 56 + w) * 256 + head * 32 + cp * 8, ov, 16);
  }
}

// ---------------- 5x5 dwconv (lepe) v4: LDS-staged row-segment tile ----------------
__global__ __launch_bounds__(256) void lepe_kernel(const unsigned short* __restrict__ qvb,
                                                   const unsigned short* __restrict__ wlep,
                                                   const float* __restrict__ b,
                                                   unsigned short* __restrict__ out) {
  __shared__ unsigned short Vs[60 * 272];
  int bid = blockIdx.x;
  int wgid = (bid & 7) * 784 + (bid >> 3);
  int tb = wgid * 8;
  int n = tb / 3136, rem = tb % 3136;
  int h0 = rem / 56, w0 = rem % 56;
  int tid = threadIdx.x;

  const unsigned short* vimg = qvb + (size_t)n * 3136 * 512 + 256;
  {
    int chunk = tid & 31;
    for (int s = tid >> 5; s < 60; s += 8) {
      int r = s / 12, cc = s % 12;
      int hh = h0 + r - 2; hh = hh < 0 ? 0 : (hh > 55 ? 55 : hh);
      int wcg = w0 + cc - 2; wcg = wcg < 0 ? 0 : (wcg > 55 ? 55 : wcg);
      unsigned short tmp[8];
      __builtin_memcpy(tmp, vimg + (size_t)(hh * 56 + wcg) * 512 + chunk * 8, 16);
      __builtin_memcpy(&Vs[s * 272 + chunk * 8], tmp, 16);
    }
  }
  __syncthreads();

  int px = tid >> 5;
  int cg = tid & 31;
  int c = cg * 8;
  int wq = w0 + px;

  float acc[8];
#pragma unroll
  for (int j = 0; j < 8; j++) acc[j] = b[c + j];

#pragma unroll
  for (int r = 0; r < 5; r++) {
    float hok = ((unsigned)(h0 + r - 2) < 56u) ? 1.f : 0.f;
#pragma unroll
    for (int dc = 0; dc < 5; dc++) {
      float m = hok * (((unsigned)(wq + dc - 2) < 56u) ? 1.f : 0.f);
      int slot = r * 12 + px + dc;
      unsigned short vv[8], wv[8];
      __builtin_memcpy(vv, &Vs[slot * 272 + cg * 8], 16);
      __builtin_memcpy(wv, wlep + (r * 5 + dc) * 256 + c, 16);
#pragma unroll
      for (int j = 0; j < 8; j++) acc[j] += bf2f(vv[j]) * (bf2f(wv[j]) * m);
    }
  }

  size_t o = (size_t)(tb + px) * 256 + c;
  unsigned short ov[8];
  __builtin_memcpy(ov, out + o, 16);
  unsigned short nv[8];
#pragma unroll
  for (int j = 0; j < 8; j++) nv[j] = f2bf(bf2f(ov[j]) + acc[j]);
  __builtin_memcpy(out + o, nv, 16);
}

// ---------------- launch ----------------
extern "C" void kernel_launch(void* const* d_in, const int* in_sizes, int n_in,
                              void* d_out, int out_size, void* d_ws, size_t ws_size,
                              hipStream_t stream) {
  const float* x      = (const float*)d_in[0];
  const float* pos_w  = (const float*)d_in[1];
  const float* pos_b  = (const float*)d_in[2];
  const float* ln1_g  = (const float*)d_in[3];
  const float* ln1_b  = (const float*)d_in[4];
  const float* ln2_g  = (const float*)d_in[5];
  const float* ln2_b  = (const float*)d_in[6];
  const float* qkv_w  = (const float*)d_in[7];
  const float* qkv_b  = (const float*)d_in[8];
  const float* wo_w   = (const float*)d_in[9];
  const float* wo_b   = (const float*)d_in[10];
  const float* lepe_w = (const float*)d_in[11];
  const float* lepe_b = (const float*)d_in[12];
  const float* fc1_w  = (const float*)d_in[13];
  const float* fc1_b  = (const float*)d_in[14];
  const float* fc2_w  = (const float*)d_in[15];
  const float* fc2_b  = (const float*)d_in[16];

  // d_out timeline: xt (f32 NHWC) -> qvb (bf16 [TOK][512]) -> final NCHW f32 (fc2 epilogue)
  float*          xt   = (float*)d_out;
  unsigned short* qvb  = (unsigned short*)d_out;
  unsigned short* hbuf = (unsigned short*)d_out;   // split-path MLP hidden (dead-qvb reuse)

  // ws arena (~101 MB base)
  float*          r2   = (float*)d_ws;
  float*          wmx  = r2 + TC;
  float*          qkw  = wmx + (size_t)784 * 256;
  float*          bqv  = qkw + (size_t)784 * 512;
  unsigned short* lnb  = (unsigned short*)(bqv + 512);
  unsigned short* aob  = lnb;
  unsigned short* ln2b = lnb;
  unsigned short* plx  = lnb + TC;
  unsigned short* kvp  = plx + (size_t)PTOK * 256;
  unsigned short* wqv  = kvp + (size_t)PTOK * 512;
  unsigned short* wkv  = wqv + (size_t)512 * 256;
  unsigned short* wwo  = wkv + (size_t)512 * 256;
  unsigned short* wfc1 = wwo + (size_t)256 * 256;
  unsigned short* wfc2 = wfc1 + (size_t)1024 * 256;
  int*            idx  = (int*)(wfc2 + (size_t)256 * 1024);
  float*          murs = (float*)(idx + 784 * 4);
  unsigned short* wlep = (unsigned short*)(murs + (size_t)TOK * 2);
  unsigned short* hfull = wlep + 6400;

  size_t base_bytes = (size_t)((char*)hfull - (char*)d_ws);
  bool fullmlp = ws_size >= base_bytes + (size_t)TOK * 1024 * 2;

  prep_kernel<<<3355, 256, 0, stream>>>(qkv_w, qkv_b, wo_w, fc1_w, fc2_w, lepe_w,
                                        wqv, wkv, wwo, wfc1, wfc2, bqv, wlep);
  nchw2nhwc<<<dim3(2, 8, NIMG * 56), 256, 0, stream>>>(x, xt);
  posln_kernel<<<TOK / 4, 256, 0, stream>>>(xt, pos_w, pos_b, ln1_g, ln1_b,
                                            r2, lnb, murs);
  pool_kernel<<<196, 256, 0, stream>>>(r2, murs, ln1_g, ln1_b, plx, wmx);
  mgemm2<true, false><<<784, 512, 0, stream>>>(lnb, 256, wqv, 256, bqv, nullptr,
                                               qvb, 512, 256, 0, 2,
                                               nullptr, nullptr, nullptr);
  mgemm2<true, false><<<196, 512, 0, stream>>>(plx, 256, wkv, 256, qkv_b + 256, nullptr,
                                               kvp, 512, 256, 0, 2,
                                               nullptr, nullptr, nullptr);
  winproj_kernel<<<784, 256, 0, stream>>>(wmx, qkv_w, qkv_b, qkw);
  topk_kernel<<<784, 64, 0, stream>>>(qkw, idx);
  attn_mfma<<<6272, 64, 0, stream>>>(qvb, kvp, idx, aob);
  lepe_kernel<<<TOK / 8, 256, 0, stream>>>(qvb, wlep, lepe_b, aob);
  mgemm2<false, true><<<392, 512, 0, stream>>>(aob, 256, wwo, 256, wo_b, r2,
                                               r2, 256, 256, 2, 1,
                                               ln2_g, ln2_b, ln2b);
  if (fullmlp) {
    mgemm2<true, false><<<1568, 512, 0, stream>>>(ln2b, 256, wfc1, 256, fc1_b, nullptr,
                                                  hfull, 1024, 256, 1, 4,
                                                  nullptr, nullptr, nullptr);
    mgemm2<false, false, true><<<392, 512, 0, stream>>>(hfull, 1024, wfc2, 1024, fc2_b, r2,
                                                        d_out, 256, 1024, 2, 1,
                                                        nullptr, nullptr, nullptr);
  } else {
    mgemm2<true, false><<<784, 512, 0, stream>>>(ln2b, 256, wfc1, 256, fc1_b, nullptr,
                                                 hbuf, 512, 256, 1, 2,
                                                 nullptr, nullptr, nullptr);
    mgemm2<false, false><<<392, 512, 0, stream>>>(hbuf, 512, wfc2, 1024, fc2_b, r2,
                                                  r2, 256, 512, 2, 1,
                                                  nullptr, nullptr, nullptr);
    mgemm2<true, false><<<784, 512, 0, stream>>>(ln2b, 256, wfc1 + (size_t)512 * 256, 256,
                                                 fc1_b + 512, nullptr,
                                                 hbuf, 512, 256, 1, 2,
                                                 nullptr, nullptr, nullptr);
    mgemm2<false, false, true><<<392, 512, 0, stream>>>(hbuf, 512, wfc2 + 512, 1024, fc2_b, r2,
                                                        d_out, 256, 512, 2 | 8, 1,
                                                        nullptr, nullptr, nullptr);
  }
}